// Round 5
// baseline (342.377 us; speedup 1.0000x reference)
//
#include <hip/hip_runtime.h>

// SoftFaceColorShader: pytorch3d-style softmax blending. Latency-bound fix:
// 2 pixels per thread -> all strides 16B-aligned (80B/240B per pair) -> dwordx4
// loads; load-everything-then-compute structure + relaxed VGPR cap so ~120
// registers of loads stay in flight (baseline was 36 VGPR, ~1 load in flight).

#define KN 8
#define KH 384
#define KW 384
#define KK 10
#define KF 20000
#define KD 3

typedef int   i32x4 __attribute__((ext_vector_type(4)));
typedef float f32x4 __attribute__((ext_vector_type(4)));

__global__ __launch_bounds__(256, 3) void soft_face_shader_kernel(
    const int*   __restrict__ p2f,    // [P, K]
    const float* __restrict__ bary,   // [P, K, 3]
    const float* __restrict__ zbuf,   // [P, K]
    const float* __restrict__ dists,  // [P, K]
    const float* __restrict__ fcol,   // [N*F, 3]
    float*       __restrict__ out,    // [P, 4]
    int nPairs)
{
    const float SIGMA = 1e-4f;
    const float GAMMA = 1e-2f;
    const float ZNEAR = 1.0f, ZFAR = 100.0f;
    const float EPS = 1e-10f;

    int t = blockIdx.x * blockDim.x + threadIdx.x;  // pixel-pair index
    if (t >= nPairs) return;

    // ---- issue ALL loads up front (consumption order: p2f, dists, zbuf, bary) ----
    i32x4 pf[5];   // 2 px x 10 ints   = 80 B
    f32x4 ds[5];   // 2 px x 10 f32
    f32x4 zb[5];   // 2 px x 10 f32
    f32x4 by[15];  // 2 px x 30 f32    = 240 B
    {
        const i32x4* p = reinterpret_cast<const i32x4*>(p2f + (size_t)t * 2 * KK);
        #pragma unroll
        for (int i = 0; i < 5; ++i) pf[i] = p[i];
    }
    {
        const f32x4* p = reinterpret_cast<const f32x4*>(dists + (size_t)t * 2 * KK);
        #pragma unroll
        for (int i = 0; i < 5; ++i) ds[i] = p[i];
    }
    {
        const f32x4* p = reinterpret_cast<const f32x4*>(zbuf + (size_t)t * 2 * KK);
        #pragma unroll
        for (int i = 0; i < 5; ++i) zb[i] = p[i];
    }
    {
        const f32x4* p = reinterpret_cast<const f32x4*>(bary + (size_t)t * 2 * KK * 3);
        #pragma unroll
        for (int i = 0; i < 15; ++i) by[i] = p[i];
    }

    // ---- pass 1: prob, z_inv, running max, alpha (2 pixels, flat j = px*10+k) ----
    float prob[2 * KK], zinv[2 * KK];
    float onem0 = 1.0f, onem1 = 1.0f;
    float zmax0 = EPS,  zmax1 = EPS;
    #pragma unroll
    for (int j = 0; j < 2 * KK; ++j) {
        int  fj = pf[j >> 2][j & 3];
        bool m  = fj >= 0;
        float tt = ds[j >> 2][j & 3] / SIGMA;
        float pr = m ? 1.0f / (1.0f + __expf(tt)) : 0.0f;   // sigmoid(-d/sigma)
        prob[j] = pr;
        float zi = m ? (ZFAR - zb[j >> 2][j & 3]) / (ZFAR - ZNEAR) : 0.0f;
        zinv[j] = zi;
        if (j < KK) { onem0 *= (1.0f - pr); zmax0 = fmaxf(zmax0, zi); }
        else        { onem1 *= (1.0f - pr); zmax1 = fmaxf(zmax1, zi); }
    }
    float alpha0 = 1.0f - onem0;
    float alpha1 = 1.0f - onem1;

    // ---- pass 2: softmax weights + color gather (fcol is L2-resident) ----
    float den0 = fmaxf(__expf((EPS - zmax0) / GAMMA), EPS);
    float den1 = fmaxf(__expf((EPS - zmax1) / GAMMA), EPS);
    float a00 = 0.f, a01 = 0.f, a02 = 0.f;
    float a10 = 0.f, a11 = 0.f, a12 = 0.f;
    #pragma unroll
    for (int j = 0; j < 2 * KK; ++j) {
        float zm = (j < KK) ? zmax0 : zmax1;
        float w  = prob[j] * __expf((zinv[j] - zm) / GAMMA);
        if (j < KK) den0 += w; else den1 += w;
        int fj = pf[j >> 2][j & 3];
        if (fj >= 0) {
            const float* c = fcol + (size_t)fj * 3;
            float bs = by[(3*j) >> 2][(3*j) & 3]
                     + by[(3*j+1) >> 2][(3*j+1) & 3]
                     + by[(3*j+2) >> 2][(3*j+2) & 3];
            float wb = w * bs;
            if (j < KK) {
                a00 = fmaf(wb, c[0], a00);
                a01 = fmaf(wb, c[1], a01);
                a02 = fmaf(wb, c[2], a02);
            } else {
                a10 = fmaf(wb, c[0], a10);
                a11 = fmaf(wb, c[1], a11);
                a12 = fmaf(wb, c[2], a12);
            }
        }
    }
    float i0 = 1.0f / den0;
    float i1 = 1.0f / den1;
    f32x4* po = reinterpret_cast<f32x4*>(out + (size_t)t * 8);
    f32x4 o0 = { a00 * i0, a01 * i0, a02 * i0, alpha0 };
    f32x4 o1 = { a10 * i1, a11 * i1, a12 * i1, alpha1 };
    po[0] = o0;
    po[1] = o1;
}

extern "C" void kernel_launch(void* const* d_in, const int* in_sizes, int n_in,
                              void* d_out, int out_size, void* d_ws, size_t ws_size,
                              hipStream_t stream) {
    const int*   p2f   = (const int*)  d_in[0];
    const float* bary  = (const float*)d_in[1];
    const float* zbuf  = (const float*)d_in[2];
    const float* dists = (const float*)d_in[3];
    const float* fcol  = (const float*)d_in[4];
    float* out = (float*)d_out;

    const int P = KN * KH * KW;       // 1,179,648 pixels
    const int nPairs = P / 2;         // 589,824 (P is even)
    const int block = 256;
    const int grid = (nPairs + block - 1) / block;  // 2304 blocks
    soft_face_shader_kernel<<<grid, block, 0, stream>>>(p2f, bary, zbuf, dists, fcol, out, nPairs);
}

// Round 9
// 334.844 us; speedup vs baseline: 1.0225x; 1.0225x over previous
//
#include <hip/hip_runtime.h>

// SoftFaceColorShader: pytorch3d-style softmax blending.
// vs round-5 (146us, VGPR=68, HBM 16.7%):
//  - sched_barrier(0) after the 30 streaming dwordx4 loads: compiler was
//    sinking loads to consumers (VGPR=68 => ~8 in flight). Fence forces all
//    30 outstanding (~480 B/lane in flight -> HBM saturation even at low occ).
//  - gather: one 12B dwordx3 load per face (exact row, no OOB) instead of 3
//    scalar dwords -> 3x fewer divergent VMEM instrs; batched behind a fence.
//  - branchless blend: masked faces have prob=0 => w=0 => contribution 0.

#define KN 8
#define KH 384
#define KW 384
#define KK 10

typedef int   i32x4 __attribute__((ext_vector_type(4)));
typedef float f32x4 __attribute__((ext_vector_type(4)));

__global__ __launch_bounds__(256, 2) void soft_face_shader_kernel(
    const int*   __restrict__ p2f,    // [P, K]
    const float* __restrict__ bary,   // [P, K, 3]
    const float* __restrict__ zbuf,   // [P, K]
    const float* __restrict__ dists,  // [P, K]
    const float* __restrict__ fcol,   // [N*F, 3]
    float*       __restrict__ out,    // [P, 4]
    int nPairs)
{
    const float SIGMA = 1e-4f;
    const float GAMMA = 1e-2f;
    const float ZNEAR = 1.0f, ZFAR = 100.0f;
    const float EPS = 1e-10f;

    int t = blockIdx.x * blockDim.x + threadIdx.x;  // pixel-pair index
    if (t >= nPairs) return;

    // ---- phase A: issue ALL streaming loads (30 x dwordx4, 480 B/lane) ----
    i32x4 pf[5];   // 2 px x 10 ints
    f32x4 dsv[5];  // 2 px x 10 f32
    f32x4 zbv[5];  // 2 px x 10 f32
    f32x4 byv[15]; // 2 px x 30 f32
    {
        const i32x4* p = reinterpret_cast<const i32x4*>(p2f + (size_t)t * 2 * KK);
        #pragma unroll
        for (int i = 0; i < 5; ++i) pf[i] = p[i];
    }
    {
        const f32x4* p = reinterpret_cast<const f32x4*>(dists + (size_t)t * 2 * KK);
        #pragma unroll
        for (int i = 0; i < 5; ++i) dsv[i] = p[i];
    }
    {
        const f32x4* p = reinterpret_cast<const f32x4*>(zbuf + (size_t)t * 2 * KK);
        #pragma unroll
        for (int i = 0; i < 5; ++i) zbv[i] = p[i];
    }
    {
        const f32x4* p = reinterpret_cast<const f32x4*>(bary + (size_t)t * 2 * KK * 3);
        #pragma unroll
        for (int i = 0; i < 15; ++i) byv[i] = p[i];
    }
    // Nothing may cross: all 30 loads must be issued before any consumer.
    __builtin_amdgcn_sched_barrier(0);

    // ---- phase B: prob, z_inv, running max, alpha ----
    float prob[2 * KK], zinv[2 * KK];
    float onem0 = 1.0f, onem1 = 1.0f;
    float zmax0 = EPS,  zmax1 = EPS;
    #pragma unroll
    for (int j = 0; j < 2 * KK; ++j) {
        int  fj = pf[j >> 2][j & 3];
        bool m  = fj >= 0;
        float tt = dsv[j >> 2][j & 3] / SIGMA;
        float pr = m ? 1.0f / (1.0f + __expf(tt)) : 0.0f;   // sigmoid(-d/sigma)
        prob[j] = pr;
        float zi = m ? (ZFAR - zbv[j >> 2][j & 3]) / (ZFAR - ZNEAR) : 0.0f;
        zinv[j] = zi;
        if (j < KK) { onem0 *= (1.0f - pr); zmax0 = fmaxf(zmax0, zi); }
        else        { onem1 *= (1.0f - pr); zmax1 = fmaxf(zmax1, zi); }
    }
    float alpha0 = 1.0f - onem0;
    float alpha1 = 1.0f - onem1;

    // ---- phase C: softmax weights * bary-sums (consumes prob/zinv/byv) ----
    float den0 = fmaxf(__expf((EPS - zmax0) / GAMMA), EPS);
    float den1 = fmaxf(__expf((EPS - zmax1) / GAMMA), EPS);
    float wb[2 * KK];
    #pragma unroll
    for (int j = 0; j < 2 * KK; ++j) {
        float zm = (j < KK) ? zmax0 : zmax1;
        float w  = prob[j] * __expf((zinv[j] - zm) / GAMMA);
        if (j < KK) den0 += w; else den1 += w;
        float bs = byv[(3*j) >> 2][(3*j) & 3]
                 + byv[(3*j+1) >> 2][(3*j+1) & 3]
                 + byv[(3*j+2) >> 2][(3*j+2) & 3];
        wb[j] = w * bs;   // masked faces: w == 0 exactly -> contribution 0
    }

    // ---- phase D: issue all 20 gather loads (12B dwordx3 each, idx clamped) ----
    float col[2 * KK][3];
    #pragma unroll
    for (int j = 0; j < 2 * KK; ++j) {
        int fj  = pf[j >> 2][j & 3];
        int idx = fj < 0 ? 0 : fj;
        // exact 12B row at 4B alignment -> global_load_dwordx3, no OOB
        __builtin_memcpy(&col[j][0], fcol + (size_t)idx * 3, 12);
    }
    // Keep the 20 gather loads grouped ahead of the blend.
    __builtin_amdgcn_sched_barrier(0);

    // ---- phase E: branchless blend ----
    float a00 = 0.f, a01 = 0.f, a02 = 0.f;
    float a10 = 0.f, a11 = 0.f, a12 = 0.f;
    #pragma unroll
    for (int j = 0; j < 2 * KK; ++j) {
        float wbj = wb[j];
        if (j < KK) {
            a00 = fmaf(wbj, col[j][0], a00);
            a01 = fmaf(wbj, col[j][1], a01);
            a02 = fmaf(wbj, col[j][2], a02);
        } else {
            a10 = fmaf(wbj, col[j][0], a10);
            a11 = fmaf(wbj, col[j][1], a11);
            a12 = fmaf(wbj, col[j][2], a12);
        }
    }
    float i0 = 1.0f / den0;
    float i1 = 1.0f / den1;
    f32x4* po = reinterpret_cast<f32x4*>(out + (size_t)t * 8);
    f32x4 o0 = { a00 * i0, a01 * i0, a02 * i0, alpha0 };
    f32x4 o1 = { a10 * i1, a11 * i1, a12 * i1, alpha1 };
    po[0] = o0;
    po[1] = o1;
}

extern "C" void kernel_launch(void* const* d_in, const int* in_sizes, int n_in,
                              void* d_out, int out_size, void* d_ws, size_t ws_size,
                              hipStream_t stream) {
    const int*   p2f   = (const int*)  d_in[0];
    const float* bary  = (const float*)d_in[1];
    const float* zbuf  = (const float*)d_in[2];
    const float* dists = (const float*)d_in[3];
    const float* fcol  = (const float*)d_in[4];
    float* out = (float*)d_out;

    const int P = KN * KH * KW;       // 1,179,648 pixels
    const int nPairs = P / 2;         // 589,824 (P is even)
    const int block = 256;
    const int grid = (nPairs + block - 1) / block;  // 2304 blocks
    soft_face_shader_kernel<<<grid, block, 0, stream>>>(p2f, bary, zbuf, dists, fcol, out, nPairs);
}